// Round 10
// baseline (2153.013 us; speedup 1.0000x reference)
//
#include <hip/hip_runtime.h>
#include <math.h>

// Problem constants
constexpr int Tn  = 2048;  // time
constexpr int FCn = 512;   // context feats (g)
constexpr int FXn = 512;   // encoding feats (x)
constexpr int SXW = 72;    // (fallback) LDS stride bf16 sX/sW
constexpr int SYC = 136;   // (fallback) LDS stride bf16 sY/sC
constexpr int SZS = 132;   // (fallback) LDS stride fp32 sZ

typedef __attribute__((ext_vector_type(8))) short  bf16x8;
typedef __attribute__((ext_vector_type(4))) float  f32x4;

// truncating fp32->bf16 pack: one v_perm_b32 per 2 elems
__device__ __forceinline__ unsigned pk2(float a, float b) {
  return __builtin_amdgcn_perm(__float_as_uint(b), __float_as_uint(a), 0x07060302u);
}
__device__ __forceinline__ uint4 pack8(float4 a, float4 b) {
  uint4 rv;
  rv.x = pk2(a.x, a.y); rv.y = pk2(a.z, a.w);
  rv.z = pk2(b.x, b.y); rv.w = pk2(b.z, b.w);
  return rv;
}

// async global->LDS 16B copy (dest = wave-uniform base + lane*16)
__device__ __forceinline__ void gll16(const unsigned short* g, void* lds) {
  __builtin_amdgcn_global_load_lds(
      (const __attribute__((address_space(1))) unsigned int*)g,
      (__attribute__((address_space(3))) unsigned int*)lds, 16, 0, 0);
}

__global__ void zero4(float* out) {
  if (threadIdx.x < 4) out[threadIdx.x] = 0.0f;
}

__global__ void finalize4(float* out) {
  int k = threadIdx.x;
  if (k < 4) out[k] *= 1.0f / (128.0f * (float)(Tn - (1 << k)));
}

// fp32 -> bf16 (trunc) converter, 4 elems/thread
__global__ void tobf16(const float* __restrict__ s, unsigned short* __restrict__ d) {
  int i = blockIdx.x * 256 + threadIdx.x;
  float4 v = ((const float4*)s)[i];
  uint2 p; p.x = pk2(v.x, v.y); p.y = pk2(v.z, v.w);
  ((uint2*)d)[i] = p;
}

// ---------------- v8 main kernel ----------------------------------------------
// One 256-thread (4-wave) block per (k,t). Y wave tile 64(j)x128(g) over gc=2
// g-chunks of 256; Z wave tile 64(i)x64(j). 2-phase double-buffered staging,
// BK=32: STAGE(next buf) issued BEFORE MFMA(current buf); single barrier/phase
// (its vmcnt(0) drain is covered by the MFMA). Both-sides XOR granule swizzle
// on 64B staging rows and on the 64KB sY. Epilogue lse fully in-register
// (shfl + 2KB stats exchange), no sZ.
// LDS: dbuf 2x24K @0; sY 64K @0 (overlays, disjoint lifetime); stats @65536.
__global__ __launch_bounds__(256, 2)
void infonce_v8(const float* __restrict__ Cp, const unsigned short* __restrict__ Xb,
                const unsigned short* __restrict__ Wb, float* __restrict__ out)
{
  __shared__ __align__(16) unsigned char smem[67648];
  char* sm = (char*)smem;
  float* stats_m = (float*)(sm + 65536);
  float* stats_s = (float*)(sm + 66560);
  float* sRed    = (float*)(sm + 67584);

  const int tid = threadIdx.x;
  const int l   = tid & 63;
  const int w   = tid >> 6;     // 0..3
  const int r   = l & 15;
  const int h   = l >> 4;       // 0..3
  const int jw  = w >> 1;       // Y: j-half
  const int gw  = w & 1;        // Y: g-half
  const int iw  = w >> 1;       // Z: i-half
  const int jw2 = w & 1;        // Z: j-half

  // bijective chunked XCD swizzle: nwg = 8188 = 8*1023 + 4
  const int orig = blockIdx.x;
  const int xcd  = orig & 7;
  const int loc  = orig >> 3;
  const int wg   = (xcd < 4) ? (xcd * 1024 + loc) : (4096 + (xcd - 4) * 1023 + loc);
  const int k    = wg & 3;
  const int t    = wg >> 2;
  const int tau  = 1 << k;      // TAU = {1,2,4,8}
  if (t >= Tn - tau) return;    // uniform early-exit, before any barrier
  const int s = t + tau;

  // staging source (pre-swizzled granule: gsw = (l&3)^((l>>3)&3), self-inverse)
  const int sub = l >> 2;                       // row within 16-row segment
  const int gsw = (l & 3) ^ ((l >> 3) & 3);     // source 16B granule
  const size_t xstr = (size_t)Tn * FXn;
  const unsigned short* xs0 = Xb + (size_t)(w * 32 + sub) * xstr
                              + (size_t)s * FXn + gsw * 8;
  const unsigned short* xs1 = xs0 + (size_t)16 * xstr;
  const unsigned short* wk  = Wb + (size_t)k * (FCn * FXn) + gsw * 8;
  const unsigned short* ws0 = wk  + (size_t)(w * 64 + sub) * FXn;
  const unsigned short* ws1 = ws0 + (size_t)16 * FXn;
  const unsigned short* ws2 = ws0 + (size_t)32 * FXn;
  const unsigned short* ws3 = ws0 + (size_t)48 * FXn;

  // C row pointers (fp32 direct; trunc->bf16 in regs)
  const size_t cstr = (size_t)Tn * FCn;
  const float* cr0 = Cp + (size_t)(iw * 64 +  0 + r) * cstr + (size_t)t * FCn;
  const float* cr1 = Cp + (size_t)(iw * 64 + 16 + r) * cstr + (size_t)t * FCn;
  const float* cr2 = Cp + (size_t)(iw * 64 + 32 + r) * cstr + (size_t)t * FCn;
  const float* cr3 = Cp + (size_t)(iw * 64 + 48 + r) * cstr + (size_t)t * FCn;

  f32x4 zacc[4][4];
#pragma unroll
  for (int a = 0; a < 4; ++a)
#pragma unroll
    for (int b = 0; b < 4; ++b) zacc[a][b] = f32x4{0.f, 0.f, 0.f, 0.f};

#define STG8(BUFC, XC) do { \
    char* _bb = sm + (BUFC) * 24576; \
    const size_t _xo = (size_t)(XC) * 32; \
    gll16(xs0 + _xo, _bb + (w * 2    ) * 1024); \
    gll16(xs1 + _xo, _bb + (w * 2 + 1) * 1024); \
    const size_t _wo = wgc + _xo; \
    gll16(ws0 + _wo, _bb + 8192 + (w * 4    ) * 1024); \
    gll16(ws1 + _wo, _bb + 8192 + (w * 4 + 1) * 1024); \
    gll16(ws2 + _wo, _bb + 8192 + (w * 4 + 2) * 1024); \
    gll16(ws3 + _wo, _bb + 8192 + (w * 4 + 3) * 1024); \
  } while (0)

#define MFY8(BUFC) do { \
    const char* _bx = sm + (BUFC) * 24576; \
    const char* _bw = _bx + 8192; \
    const int _gb = (h ^ ((r >> 1) & 3)) << 4; \
    bf16x8 _ax[4]; \
    _Pragma("unroll") \
    for (int _bm = 0; _bm < 4; ++_bm) \
      _ax[_bm] = *(const bf16x8*)(_bx + (jw * 64 + _bm * 16 + r) * 64 + _gb); \
    bf16x8 _bv[8]; \
    _Pragma("unroll") \
    for (int _bn = 0; _bn < 8; ++_bn) \
      _bv[_bn] = *(const bf16x8*)(_bw + (gw * 128 + _bn * 16 + r) * 64 + _gb); \
    _Pragma("unroll") \
    for (int _bm = 0; _bm < 4; ++_bm) \
      _Pragma("unroll") \
      for (int _bn = 0; _bn < 8; ++_bn) \
        yacc[_bm][_bn] = __builtin_amdgcn_mfma_f32_16x16x32_bf16( \
            _ax[_bm], _bv[_bn], yacc[_bm][_bn], 0, 0, 0); \
  } while (0)

#pragma unroll 1
  for (int gc = 0; gc < 2; ++gc) {
    const size_t wgc = (size_t)gc * 256 * FXn;
    f32x4 yacc[4][8];
#pragma unroll
    for (int a = 0; a < 4; ++a)
#pragma unroll
      for (int b = 0; b < 8; ++b) yacc[a][b] = f32x4{0.f, 0.f, 0.f, 0.f};

    STG8(0, 0);          // prologue (un-overlapped, once per gc)
    __syncthreads();
#pragma unroll 1
    for (int xc2 = 0; xc2 < 8; ++xc2) {
      STG8(1, 2 * xc2 + 1);        // loads fly under this phase's MFMA
      MFY8(0);
      __syncthreads();             // drains stage; buf1 ready, buf0 reads done
      if (xc2 < 7) STG8(0, 2 * xc2 + 2);
      MFY8(1);
      __syncthreads();
    }

    // Y -> sY (64KB, row stride 512B, XOR-granule swizzled)
#pragma unroll
    for (int bm = 0; bm < 4; ++bm)
#pragma unroll
      for (int bn = 0; bn < 8; ++bn)
#pragma unroll
        for (int reg = 0; reg < 4; ++reg) {
          const int row = jw * 64 + bm * 16 + h * 4 + reg;
          const int col = gw * 128 + bn * 16 + r;
          *(unsigned short*)(sm + row * 512 + ((col * 2) ^ ((row & 7) << 4))) =
              (unsigned short)(__float_as_uint(yacc[bm][bn][reg]) >> 16);
        }
    __syncthreads();

    // Z-GEMM: zacc[i-tile][j-tile] += C (global fp32->bf16) * Y (sY), K=256
    const int swz = (r & 7) << 4;
#pragma unroll 2
    for (int ks2 = 0; ks2 < 8; ++ks2) {
      const int goff = gc * 256 + ks2 * 32 + h * 8;
      float4 u0 = *(const float4*)(cr0 + goff), p0 = *(const float4*)(cr0 + goff + 4);
      float4 u1 = *(const float4*)(cr1 + goff), p1 = *(const float4*)(cr1 + goff + 4);
      float4 u2 = *(const float4*)(cr2 + goff), p2 = *(const float4*)(cr2 + goff + 4);
      float4 u3 = *(const float4*)(cr3 + goff), p3 = *(const float4*)(cr3 + goff + 4);
      bf16x8 acv[4];
      acv[0] = __builtin_bit_cast(bf16x8, pack8(u0, p0));
      acv[1] = __builtin_bit_cast(bf16x8, pack8(u1, p1));
      acv[2] = __builtin_bit_cast(bf16x8, pack8(u2, p2));
      acv[3] = __builtin_bit_cast(bf16x8, pack8(u3, p3));
      const int gb = ks2 * 64 + h * 16;
      bf16x8 byv[4];
#pragma unroll
      for (int bn = 0; bn < 4; ++bn)
        byv[bn] = *(const bf16x8*)(sm + (jw2 * 64 + bn * 16 + r) * 512 + (gb ^ swz));
#pragma unroll
      for (int bm = 0; bm < 4; ++bm)
#pragma unroll
        for (int bn = 0; bn < 4; ++bn)
          zacc[bm][bn] = __builtin_amdgcn_mfma_f32_16x16x32_bf16(
              acv[bm], byv[bn], zacc[bm][bn], 0, 0, 0);
    }
    __syncthreads();   // sY reads done before next gc's staging overwrites it
  }

  // ---- in-register lse epilogue ----
  // zacc: row = iw*64+bm*16+h*4+reg, col = jw2*64+bn*16+r
  float gm[4][4], tot[4][4];
#pragma unroll
  for (int bm = 0; bm < 4; ++bm)
#pragma unroll
    for (int reg = 0; reg < 4; ++reg) {
      float m = fmaxf(fmaxf(zacc[bm][0][reg], zacc[bm][1][reg]),
                      fmaxf(zacc[bm][2][reg], zacc[bm][3][reg]));
      m = fmaxf(m, __shfl_xor(m, 1));
      m = fmaxf(m, __shfl_xor(m, 2));
      m = fmaxf(m, __shfl_xor(m, 4));
      m = fmaxf(m, __shfl_xor(m, 8));
      gm[bm][reg] = m;
      if (r == 0) stats_m[jw2 * 128 + iw * 64 + bm * 16 + h * 4 + reg] = m;
    }
  __syncthreads();
#pragma unroll
  for (int bm = 0; bm < 4; ++bm)
#pragma unroll
    for (int reg = 0; reg < 4; ++reg)
      gm[bm][reg] = fmaxf(gm[bm][reg],
          stats_m[(jw2 ^ 1) * 128 + iw * 64 + bm * 16 + h * 4 + reg]);
#pragma unroll
  for (int bm = 0; bm < 4; ++bm)
#pragma unroll
    for (int reg = 0; reg < 4; ++reg) {
      float sv = __expf(zacc[bm][0][reg] - gm[bm][reg])
               + __expf(zacc[bm][1][reg] - gm[bm][reg])
               + __expf(zacc[bm][2][reg] - gm[bm][reg])
               + __expf(zacc[bm][3][reg] - gm[bm][reg]);
      sv += __shfl_xor(sv, 1);
      sv += __shfl_xor(sv, 2);
      sv += __shfl_xor(sv, 4);
      sv += __shfl_xor(sv, 8);
      tot[bm][reg] = sv;
      if (r == 0) stats_s[jw2 * 128 + iw * 64 + bm * 16 + h * 4 + reg] = sv;
    }
  __syncthreads();
#pragma unroll
  for (int bm = 0; bm < 4; ++bm)
#pragma unroll
    for (int reg = 0; reg < 4; ++reg)
      tot[bm][reg] += stats_s[(jw2 ^ 1) * 128 + iw * 64 + bm * 16 + h * 4 + reg];

  float val = 0.f;
  if (iw == jw2) {   // diagonal lives in waves with iw == jw2
#pragma unroll
    for (int bm = 0; bm < 4; ++bm)
#pragma unroll
      for (int reg = 0; reg < 4; ++reg)
        if (r == h * 4 + reg)
          val += zacc[bm][bm][reg] - (__logf(tot[bm][reg]) + gm[bm][reg]);
  }
#pragma unroll
  for (int off = 1; off < 64; off <<= 1) val += __shfl_xor(val, off);
  if (l == 0) sRed[w] = val;
  __syncthreads();
  if (tid == 0) atomicAdd(out + k, sRed[0] + sRed[1] + sRed[2] + sRed[3]);
#undef STG8
#undef MFY8
}

// ---------------- R5 fallback kernel (proven 1483 us) --------------------------
template <bool WBF>
__global__ __launch_bounds__(512, 4)
void infonce_main(const float* __restrict__ Cp, const float* __restrict__ Xp,
                  const void* __restrict__ Wp, float* __restrict__ out)
{
  __shared__ __align__(16) unsigned char smem[71680];
  unsigned short* sX = (unsigned short*)(smem);
  unsigned short* sW = (unsigned short*)(smem + 18432);
  unsigned short* sY = (unsigned short*)(smem + 36864);
  unsigned short* sC = (unsigned short*)(smem);
  float* sZ   = (float*)(smem);
  float* sRed = (float*)(smem + 67584);

  const int tid  = threadIdx.x;
  const int lane = tid & 63;
  const int wave = tid >> 6;
  const int r    = lane & 15;
  const int h    = lane >> 4;
  const int wr   = wave >> 1;
  const int wc   = wave & 1;

  const int orig = blockIdx.x;
  const int xcd  = orig & 7;
  const int loc  = orig >> 3;
  const int wg   = (xcd < 4) ? (xcd * 1024 + loc) : (4096 + (xcd - 4) * 1023 + loc);
  const int k    = wg & 3;
  const int t    = wg >> 2;
  const int tau  = 1 << k;
  if (t >= Tn - tau) return;

  const float* Cb = Cp + (size_t)t * FCn;
  const float* Xb = Xp + (size_t)(t + tau) * FXn;

  const int srow = tid >> 2;
  const int scol = (tid & 3) * 16;
  const float* xs = Xb + (size_t)srow * (Tn * FXn) + scol;
  unsigned short* xd = sX + srow * SXW + scol;
  unsigned short* wd = sW + srow * SXW + scol;
  const unsigned short* wsh = (const unsigned short*)Wp + (size_t)k * (FCn * FXn)
                              + (size_t)srow * FXn + scol;
  const float* wsf = (const float*)Wp + (size_t)k * (FCn * FXn)
                     + (size_t)srow * FXn + scol;
  const int crow0 = tid >> 4;
  const int ccol  = (tid & 15) * 8;
  const float* cs = Cb + (size_t)crow0 * (Tn * FCn) + ccol;
  unsigned short* cd = sC + crow0 * SYC + ccol;
  const size_t cstep = (size_t)32 * Tn * FCn;

  float4 px0, px1, px2, px3;
  float4 pw0, pw1, pw2, pw3;
  uint4  pb0, pb1;
  float4 pc0, pc1, pc2, pc3, pc4, pc5, pc6, pc7;

#define LOAD_X(XC) do { \
    const float4* _p = (const float4*)(xs + (XC) * 64); \
    px0 = _p[0]; px1 = _p[1]; px2 = _p[2]; px3 = _p[3]; } while (0)
#define LOAD_W(GC, XC) do { \
    if constexpr (WBF) { \
      const uint4* _p = (const uint4*)(wsh + (size_t)((GC) * 128) * FXn + (XC) * 64); \
      pb0 = _p[0]; pb1 = _p[1]; \
    } else { \
      const float4* _p = (const float4*)(wsf + (size_t)((GC) * 128) * FXn + (XC) * 64); \
      pw0 = _p[0]; pw1 = _p[1]; pw2 = _p[2]; pw3 = _p[3]; } } while (0)
#define STORE_XW() do { \
    *(uint4*)(xd)     = pack8(px0, px1); \
    *(uint4*)(xd + 8) = pack8(px2, px3); \
    if constexpr (WBF) { *(uint4*)(wd) = pb0; *(uint4*)(wd + 8) = pb1; } \
    else { *(uint4*)(wd) = pack8(pw0, pw1); *(uint4*)(wd + 8) = pack8(pw2, pw3); } \
  } while (0)
#define MFMA_YF() do { \
    _Pragma("unroll") \
    for (int ks = 0; ks < 2; ++ks) { \
      const int xoo = ks * 32 + h * 8; \
      bf16x8 a0 = *(const bf16x8*)(sX + (wr * 32 + 0  + r) * SXW + xoo); \
      bf16x8 a1 = *(const bf16x8*)(sX + (wr * 32 + 16 + r) * SXW + xoo); \
      _Pragma("unroll") \
      for (int bg = 0; bg < 4; ++bg) { \
        bf16x8 bb = *(const bf16x8*)(sW + (wc * 64 + bg * 16 + r) * SXW + xoo); \
        yacc[0][bg] = __builtin_amdgcn_mfma_f32_16x16x32_bf16(a0, bb, yacc[0][bg], 0, 0, 0); \
        yacc[1][bg] = __builtin_amdgcn_mfma_f32_16x16x32_bf16(a1, bb, yacc[1][bg], 0, 0, 0); \
      } } } while (0)

  f32x4 zacc[2][4];
#pragma unroll
  for (int a = 0; a < 2; ++a)
#pragma unroll
    for (int b = 0; b < 4; ++b) zacc[a][b] = f32x4{0.f, 0.f, 0.f, 0.f};

  LOAD_X(0); LOAD_W(0, 0);

  for (int gc = 0; gc < 4; ++gc) {
    f32x4 yacc[2][4];
#pragma unroll
    for (int a = 0; a < 2; ++a)
#pragma unroll
      for (int b = 0; b < 4; ++b) yacc[a][b] = f32x4{0.f, 0.f, 0.f, 0.f};

    for (int xc = 0; xc < 7; ++xc) {
      __syncthreads();
      STORE_XW();
      __syncthreads();
      LOAD_X(xc + 1); LOAD_W(gc, xc + 1);
      MFMA_YF();
    }
    __syncthreads();
    STORE_XW();
    __syncthreads();
    {
      const float4* p0 = (const float4*)(cs + 0 * cstep + gc * 128);
      const float4* p1 = (const float4*)(cs + 1 * cstep + gc * 128);
      const float4* p2 = (const float4*)(cs + 2 * cstep + gc * 128);
      const float4* p3 = (const float4*)(cs + 3 * cstep + gc * 128);
      pc0 = p0[0]; pc1 = p0[1];
      pc2 = p1[0]; pc3 = p1[1];
      pc4 = p2[0]; pc5 = p2[1];
      pc6 = p3[0]; pc7 = p3[1];
    }
    MFMA_YF();

#pragma unroll
    for (int aj = 0; aj < 2; ++aj)
#pragma unroll
      for (int bg = 0; bg < 4; ++bg)
#pragma unroll
        for (int reg = 0; reg < 4; ++reg)
          sY[(wr * 32 + aj * 16 + h * 4 + reg) * SYC + (wc * 64 + bg * 16 + r)] =
              (unsigned short)(__float_as_uint(yacc[aj][bg][reg]) >> 16);
    __syncthreads();
    *(uint4*)(cd + 0 * 32 * SYC) = pack8(pc0, pc1);
    *(uint4*)(cd + 1 * 32 * SYC) = pack8(pc2, pc3);
    *(uint4*)(cd + 2 * 32 * SYC) = pack8(pc4, pc5);
    *(uint4*)(cd + 3 * 32 * SYC) = pack8(pc6, pc7);
    __syncthreads();
    if (gc < 3) { LOAD_X(0); LOAD_W(gc + 1, 0); }
#pragma unroll
    for (int ks = 0; ks < 4; ++ks) {
      const int go = ks * 32 + h * 8;
      bf16x8 a0 = *(const bf16x8*)(sC + (wr * 32 + 0  + r) * SYC + go);
      bf16x8 a1 = *(const bf16x8*)(sC + (wr * 32 + 16 + r) * SYC + go);
#pragma unroll
      for (int bj = 0; bj < 4; ++bj) {
        bf16x8 bb = *(const bf16x8*)(sY + (wc * 64 + bj * 16 + r) * SYC + go);
        zacc[0][bj] = __builtin_amdgcn_mfma_f32_16x16x32_bf16(a0, bb, zacc[0][bj], 0, 0, 0);
        zacc[1][bj] = __builtin_amdgcn_mfma_f32_16x16x32_bf16(a1, bb, zacc[1][bj], 0, 0, 0);
      }
    }
  }
  __syncthreads();
#pragma unroll
  for (int ai = 0; ai < 2; ++ai)
#pragma unroll
    for (int bj = 0; bj < 4; ++bj)
#pragma unroll
      for (int reg = 0; reg < 4; ++reg)
        sZ[(wr * 32 + ai * 16 + h * 4 + reg) * SZS + (wc * 64 + bj * 16 + r)] =
            zacc[ai][bj][reg];
  __syncthreads();

  const int row = wave * 16 + (lane >> 2);
  const int c0l = lane & 3;
  float mx = -3.4e38f;
#pragma unroll
  for (int m = 0; m < 32; ++m) mx = fmaxf(mx, sZ[row * SZS + c0l + m * 4]);
  mx = fmaxf(mx, __shfl_xor(mx, 1));
  mx = fmaxf(mx, __shfl_xor(mx, 2));
  float sum = 0.f;
#pragma unroll
  for (int m = 0; m < 32; ++m) sum += __expf(sZ[row * SZS + c0l + m * 4] - mx);
  sum += __shfl_xor(sum, 1);
  sum += __shfl_xor(sum, 2);
  float val = (c0l == 0) ? (sZ[row * SZS + row] - (__logf(sum) + mx)) : 0.f;
#pragma unroll
  for (int off = 1; off < 64; off <<= 1) val += __shfl_xor(val, off);
  if (lane == 0) sRed[wave] = val;
  __syncthreads();
  if (tid == 0) {
    float bs = 0.f;
#pragma unroll
    for (int w2 = 0; w2 < 8; ++w2) bs += sRed[w2];
    atomicAdd(out + k, bs);
  }
#undef LOAD_X
#undef LOAD_W
#undef STORE_XW
#undef MFMA_YF
}

extern "C" void kernel_launch(void* const* d_in, const int* in_sizes, int n_in,
                              void* d_out, int out_size, void* d_ws, size_t ws_size,
                              hipStream_t stream) {
  const float* C = (const float*)d_in[0];
  const float* X = (const float*)d_in[1];
  const float* W = (const float*)d_in[2];
  // d_in[3] (bias) intentionally unused: j-independent bias cancels in Zdiag - lse
  float* out = (float*)d_out;

  const size_t NX = (size_t)128 * Tn * FXn;        // 134,217,728 elems (X)
  const size_t NW = (size_t)4 * FCn * FXn;         // 1,048,576 elems
  const size_t WS_W   = NW * 2;                    // 2 MB
  const size_t WS_MID = WS_W + NX * 2;             // + Xbf = 270,532,608

  hipLaunchKernelGGL(zero4, dim3(1), dim3(64), 0, stream, out);

  if (ws_size >= WS_MID) {
    unsigned short* Wbf = (unsigned short*)d_ws;
    unsigned short* Xbf = (unsigned short*)((char*)d_ws + WS_W);
    hipLaunchKernelGGL(tobf16, dim3((unsigned)(NW / 1024)), dim3(256), 0, stream, W, Wbf);
    hipLaunchKernelGGL(tobf16, dim3((unsigned)(NX / 1024)), dim3(256), 0, stream, X, Xbf);
    hipLaunchKernelGGL(infonce_v8, dim3(2047 * 4), dim3(256), 0, stream,
                       C, Xbf, Wbf, out);
  } else if (ws_size >= WS_W) {
    hipLaunchKernelGGL(tobf16, dim3((unsigned)(NW / 1024)), dim3(256), 0, stream,
                       W, (unsigned short*)d_ws);
    hipLaunchKernelGGL(infonce_main<true>, dim3(2047 * 4), dim3(512), 0, stream,
                       C, X, (const void*)d_ws, out);
  } else {
    hipLaunchKernelGGL(infonce_main<false>, dim3(2047 * 4), dim3(512), 0, stream,
                       C, X, (const void*)W, out);
  }
  hipLaunchKernelGGL(finalize4, dim3(1), dim3(64), 0, stream, out);
}

// Round 11
// 1531.830 us; speedup vs baseline: 1.4055x; 1.4055x over previous
//
#include <hip/hip_runtime.h>
#include <math.h>

// Problem constants
constexpr int Tn  = 2048;  // time
constexpr int FCn = 512;   // context feats (g)
constexpr int FXn = 512;   // encoding feats (x)
constexpr int SXW = 72;    // (fallback) LDS stride bf16 sX/sW
constexpr int SYC = 136;   // (fallback) LDS stride bf16 sY/sC
constexpr int SZS = 132;   // LDS stride fp32 sZ

typedef __attribute__((ext_vector_type(8))) short  bf16x8;
typedef __attribute__((ext_vector_type(4))) float  f32x4;

// truncating fp32->bf16 pack: one v_perm_b32 per 2 elems
__device__ __forceinline__ unsigned pk2(float a, float b) {
  return __builtin_amdgcn_perm(__float_as_uint(b), __float_as_uint(a), 0x07060302u);
}
__device__ __forceinline__ uint4 pack8(float4 a, float4 b) {
  uint4 rv;
  rv.x = pk2(a.x, a.y); rv.y = pk2(a.z, a.w);
  rv.z = pk2(b.x, b.y); rv.w = pk2(b.z, b.w);
  return rv;
}

// async global->LDS 16B copy (dest = wave-uniform base + lane*16)
__device__ __forceinline__ void gll16(const unsigned short* g, void* lds) {
  __builtin_amdgcn_global_load_lds(
      (const __attribute__((address_space(1))) unsigned int*)g,
      (__attribute__((address_space(3))) unsigned int*)lds, 16, 0, 0);
}

__global__ void zero4(float* out) {
  if (threadIdx.x < 4) out[threadIdx.x] = 0.0f;
}

__global__ void finalize4(float* out) {
  int k = threadIdx.x;
  if (k < 4) out[k] *= 1.0f / (128.0f * (float)(Tn - (1 << k)));
}

// fp32 -> bf16 (trunc) converter, 4 elems/thread
__global__ void tobf16(const float* __restrict__ s, unsigned short* __restrict__ d) {
  int i = blockIdx.x * 256 + threadIdx.x;
  float4 v = ((const float4*)s)[i];
  uint2 p; p.x = pk2(v.x, v.y); p.y = pk2(v.z, v.w);
  ((uint2*)d)[i] = p;
}

// ---------------- v9 main kernel (v8 pipeline + v7 no-spill epilogue) ----------
// One 256-thread (4-wave) block per (k,t). Y wave tile 64(j)x128(g) over gc=2
// g-chunks of 256; Z wave tile 64(i)x64(j). Double-buffered BK=32 staging via
// global_load_lds: STAGE(other buf) issued BEFORE MFMA(current buf) so the
// barrier's vmcnt(0) drain is covered by MFMA work. XOR-granule swizzle on the
// 64B staging rows (both-sides: pre-swizzled source + swizzled ds_read).
// Y->sY padded stride-528 write; Z reads sY at 528; sZ-dump + 2-lane/row lse
// epilogue (v7's proven no-spill form -- v8's in-register lse spilled 793 MB).
// LDS: dbuf 2x24K @0; sY [128][528B]=67.6K overlays (disjoint lifetime);
// sZ fp32 [128][132] overlays; sRed @67584.
__global__ __launch_bounds__(256, 2)
void infonce_v9(const float* __restrict__ Cp, const unsigned short* __restrict__ Xb,
                const unsigned short* __restrict__ Wb, float* __restrict__ out)
{
  __shared__ __align__(16) unsigned char smem[67648];
  char* sm = (char*)smem;
  float* sZ   = (float*)sm;
  float* sRed = (float*)(sm + 67584);

  const int tid = threadIdx.x;
  const int l   = tid & 63;
  const int w   = tid >> 6;     // 0..3
  const int r   = l & 15;
  const int h   = l >> 4;       // 0..3
  const int jw  = w >> 1;       // Y: j-half
  const int gw  = w & 1;        // Y: g-half
  const int iw  = w >> 1;       // Z: i-half
  const int jw2 = w & 1;        // Z: j-half

  // bijective chunked XCD swizzle: nwg = 8188 = 8*1023 + 4
  const int orig = blockIdx.x;
  const int xcd  = orig & 7;
  const int loc  = orig >> 3;
  const int wg   = (xcd < 4) ? (xcd * 1024 + loc) : (4096 + (xcd - 4) * 1023 + loc);
  const int k    = wg & 3;
  const int t    = wg >> 2;
  const int tau  = 1 << k;      // TAU = {1,2,4,8}
  if (t >= Tn - tau) return;    // uniform early-exit, before any barrier
  const int s = t + tau;

  // staging source (pre-swizzled granule: gsw = (l&3)^((l>>3)&3), self-inverse)
  const int sub = l >> 2;                       // row within 16-row segment
  const int gsw = (l & 3) ^ ((l >> 3) & 3);     // source 16B granule
  const size_t xstr = (size_t)Tn * FXn;
  const unsigned short* xs0 = Xb + (size_t)(w * 32 + sub) * xstr
                              + (size_t)s * FXn + gsw * 8;
  const unsigned short* xs1 = xs0 + (size_t)16 * xstr;
  const unsigned short* wk  = Wb + (size_t)k * (FCn * FXn) + gsw * 8;
  const unsigned short* ws0 = wk  + (size_t)(w * 64 + sub) * FXn;
  const unsigned short* ws1 = ws0 + (size_t)16 * FXn;
  const unsigned short* ws2 = ws0 + (size_t)32 * FXn;
  const unsigned short* ws3 = ws0 + (size_t)48 * FXn;

  // C row pointers (fp32 direct; trunc->bf16 in regs)
  const size_t cstr = (size_t)Tn * FCn;
  const float* cr0 = Cp + (size_t)(iw * 64 +  0 + r) * cstr + (size_t)t * FCn;
  const float* cr1 = Cp + (size_t)(iw * 64 + 16 + r) * cstr + (size_t)t * FCn;
  const float* cr2 = Cp + (size_t)(iw * 64 + 32 + r) * cstr + (size_t)t * FCn;
  const float* cr3 = Cp + (size_t)(iw * 64 + 48 + r) * cstr + (size_t)t * FCn;

  f32x4 zacc[4][4];
#pragma unroll
  for (int a = 0; a < 4; ++a)
#pragma unroll
    for (int b = 0; b < 4; ++b) zacc[a][b] = f32x4{0.f, 0.f, 0.f, 0.f};

#define STG8(BUFC, XC) do { \
    char* _bb = sm + (BUFC) * 24576; \
    const size_t _xo = (size_t)(XC) * 32; \
    gll16(xs0 + _xo, _bb + (w * 2    ) * 1024); \
    gll16(xs1 + _xo, _bb + (w * 2 + 1) * 1024); \
    const size_t _wo = wgc + _xo; \
    gll16(ws0 + _wo, _bb + 8192 + (w * 4    ) * 1024); \
    gll16(ws1 + _wo, _bb + 8192 + (w * 4 + 1) * 1024); \
    gll16(ws2 + _wo, _bb + 8192 + (w * 4 + 2) * 1024); \
    gll16(ws3 + _wo, _bb + 8192 + (w * 4 + 3) * 1024); \
  } while (0)

#define MFY8(BUFC) do { \
    const char* _bx = sm + (BUFC) * 24576; \
    const char* _bw = _bx + 8192; \
    const int _gb = (h ^ ((r >> 1) & 3)) << 4; \
    bf16x8 _ax[4]; \
    _Pragma("unroll") \
    for (int _bm = 0; _bm < 4; ++_bm) \
      _ax[_bm] = *(const bf16x8*)(_bx + (jw * 64 + _bm * 16 + r) * 64 + _gb); \
    bf16x8 _bv[8]; \
    _Pragma("unroll") \
    for (int _bn = 0; _bn < 8; ++_bn) \
      _bv[_bn] = *(const bf16x8*)(_bw + (gw * 128 + _bn * 16 + r) * 64 + _gb); \
    _Pragma("unroll") \
    for (int _bm = 0; _bm < 4; ++_bm) \
      _Pragma("unroll") \
      for (int _bn = 0; _bn < 8; ++_bn) \
        yacc[_bm][_bn] = __builtin_amdgcn_mfma_f32_16x16x32_bf16( \
            _ax[_bm], _bv[_bn], yacc[_bm][_bn], 0, 0, 0); \
  } while (0)

#pragma unroll 1
  for (int gc = 0; gc < 2; ++gc) {
    const size_t wgc = (size_t)gc * 256 * FXn;
    f32x4 yacc[4][8];
#pragma unroll
    for (int a = 0; a < 4; ++a)
#pragma unroll
      for (int b = 0; b < 8; ++b) yacc[a][b] = f32x4{0.f, 0.f, 0.f, 0.f};

    STG8(0, 0);          // prologue (un-overlapped, once per gc)
    __syncthreads();
#pragma unroll 1
    for (int xc2 = 0; xc2 < 8; ++xc2) {
      STG8(1, 2 * xc2 + 1);        // loads fly under this phase's MFMA
      MFY8(0);
      __syncthreads();             // drains stage; buf1 ready, buf0 reads done
      if (xc2 < 7) STG8(0, 2 * xc2 + 2);
      MFY8(1);
      __syncthreads();
    }

    // Y -> sY (padded stride 528 B, v7-style)
#pragma unroll
    for (int bm = 0; bm < 4; ++bm)
#pragma unroll
      for (int bn = 0; bn < 8; ++bn)
#pragma unroll
        for (int reg = 0; reg < 4; ++reg) {
          const int row = jw * 64 + bm * 16 + h * 4 + reg;
          const int col = gw * 128 + bn * 16 + r;
          *(unsigned short*)(sm + row * 528 + col * 2) =
              (unsigned short)(__float_as_uint(yacc[bm][bn][reg]) >> 16);
        }
    __syncthreads();

    // Z-GEMM: zacc += C (global fp32->bf16) * Y (sY), K=256
#pragma unroll 2
    for (int ks2 = 0; ks2 < 8; ++ks2) {
      const int goff = gc * 256 + ks2 * 32 + h * 8;
      float4 u0 = *(const float4*)(cr0 + goff), p0 = *(const float4*)(cr0 + goff + 4);
      float4 u1 = *(const float4*)(cr1 + goff), p1 = *(const float4*)(cr1 + goff + 4);
      float4 u2 = *(const float4*)(cr2 + goff), p2 = *(const float4*)(cr2 + goff + 4);
      float4 u3 = *(const float4*)(cr3 + goff), p3 = *(const float4*)(cr3 + goff + 4);
      bf16x8 acv[4];
      acv[0] = __builtin_bit_cast(bf16x8, pack8(u0, p0));
      acv[1] = __builtin_bit_cast(bf16x8, pack8(u1, p1));
      acv[2] = __builtin_bit_cast(bf16x8, pack8(u2, p2));
      acv[3] = __builtin_bit_cast(bf16x8, pack8(u3, p3));
      const int gb = ks2 * 64 + h * 16;
      bf16x8 byv[4];
#pragma unroll
      for (int bn = 0; bn < 4; ++bn)
        byv[bn] = *(const bf16x8*)(sm + (jw2 * 64 + bn * 16 + r) * 528 + gb);
#pragma unroll
      for (int bm = 0; bm < 4; ++bm)
#pragma unroll
        for (int bn = 0; bn < 4; ++bn)
          zacc[bm][bn] = __builtin_amdgcn_mfma_f32_16x16x32_bf16(
              acv[bm], byv[bn], zacc[bm][bn], 0, 0, 0);
    }
    __syncthreads();   // sY reads done before next gc's staging overwrites it
  }

  // ---- v7-style epilogue: dump Z to LDS fp32 (frees zacc), then row-lse ----
#pragma unroll
  for (int bm = 0; bm < 4; ++bm)
#pragma unroll
    for (int bn = 0; bn < 4; ++bn)
#pragma unroll
      for (int reg = 0; reg < 4; ++reg)
        sZ[(iw * 64 + bm * 16 + h * 4 + reg) * SZS + (jw2 * 64 + bn * 16 + r)] =
            zacc[bm][bn][reg];
  __syncthreads();

  // per-row lse over j (128 cols); 4 waves x 32 rows, 2 lanes per row
  const int row = w * 32 + (l >> 1);
  const int c0l = l & 1;
  float mx = -3.4e38f;
#pragma unroll
  for (int m = 0; m < 64; ++m) mx = fmaxf(mx, sZ[row * SZS + c0l + m * 2]);
  mx = fmaxf(mx, __shfl_xor(mx, 1));
  float sum = 0.f;
#pragma unroll
  for (int m = 0; m < 64; ++m) sum += __expf(sZ[row * SZS + c0l + m * 2] - mx);
  sum += __shfl_xor(sum, 1);
  float val = (c0l == 0) ? (sZ[row * SZS + row] - (__logf(sum) + mx)) : 0.f;
#pragma unroll
  for (int off = 1; off < 64; off <<= 1) val += __shfl_xor(val, off);
  if (l == 0) sRed[w] = val;
  __syncthreads();
  if (tid == 0) atomicAdd(out + k, sRed[0] + sRed[1] + sRed[2] + sRed[3]);
#undef STG8
#undef MFY8
}

// ---------------- R5 fallback kernel (proven 1483 us) --------------------------
template <bool WBF>
__global__ __launch_bounds__(512, 4)
void infonce_main(const float* __restrict__ Cp, const float* __restrict__ Xp,
                  const void* __restrict__ Wp, float* __restrict__ out)
{
  __shared__ __align__(16) unsigned char smem[71680];
  unsigned short* sX = (unsigned short*)(smem);
  unsigned short* sW = (unsigned short*)(smem + 18432);
  unsigned short* sY = (unsigned short*)(smem + 36864);
  unsigned short* sC = (unsigned short*)(smem);
  float* sZ   = (float*)(smem);
  float* sRed = (float*)(smem + 67584);

  const int tid  = threadIdx.x;
  const int lane = tid & 63;
  const int wave = tid >> 6;
  const int r    = lane & 15;
  const int h    = lane >> 4;
  const int wr   = wave >> 1;
  const int wc   = wave & 1;

  const int orig = blockIdx.x;
  const int xcd  = orig & 7;
  const int loc  = orig >> 3;
  const int wg   = (xcd < 4) ? (xcd * 1024 + loc) : (4096 + (xcd - 4) * 1023 + loc);
  const int k    = wg & 3;
  const int t    = wg >> 2;
  const int tau  = 1 << k;
  if (t >= Tn - tau) return;

  const float* Cb = Cp + (size_t)t * FCn;
  const float* Xb = Xp + (size_t)(t + tau) * FXn;

  const int srow = tid >> 2;
  const int scol = (tid & 3) * 16;
  const float* xs = Xb + (size_t)srow * (Tn * FXn) + scol;
  unsigned short* xd = sX + srow * SXW + scol;
  unsigned short* wd = sW + srow * SXW + scol;
  const unsigned short* wsh = (const unsigned short*)Wp + (size_t)k * (FCn * FXn)
                              + (size_t)srow * FXn + scol;
  const float* wsf = (const float*)Wp + (size_t)k * (FCn * FXn)
                     + (size_t)srow * FXn + scol;
  const int crow0 = tid >> 4;
  const int ccol  = (tid & 15) * 8;
  const float* cs = Cb + (size_t)crow0 * (Tn * FCn) + ccol;
  unsigned short* cd = sC + crow0 * SYC + ccol;
  const size_t cstep = (size_t)32 * Tn * FCn;

  float4 px0, px1, px2, px3;
  float4 pw0, pw1, pw2, pw3;
  uint4  pb0, pb1;
  float4 pc0, pc1, pc2, pc3, pc4, pc5, pc6, pc7;

#define LOAD_X(XC) do { \
    const float4* _p = (const float4*)(xs + (XC) * 64); \
    px0 = _p[0]; px1 = _p[1]; px2 = _p[2]; px3 = _p[3]; } while (0)
#define LOAD_W(GC, XC) do { \
    if constexpr (WBF) { \
      const uint4* _p = (const uint4*)(wsh + (size_t)((GC) * 128) * FXn + (XC) * 64); \
      pb0 = _p[0]; pb1 = _p[1]; \
    } else { \
      const float4* _p = (const float4*)(wsf + (size_t)((GC) * 128) * FXn + (XC) * 64); \
      pw0 = _p[0]; pw1 = _p[1]; pw2 = _p[2]; pw3 = _p[3]; } } while (0)
#define STORE_XW() do { \
    *(uint4*)(xd)     = pack8(px0, px1); \
    *(uint4*)(xd + 8) = pack8(px2, px3); \
    if constexpr (WBF) { *(uint4*)(wd) = pb0; *(uint4*)(wd + 8) = pb1; } \
    else { *(uint4*)(wd) = pack8(pw0, pw1); *(uint4*)(wd + 8) = pack8(pw2, pw3); } \
  } while (0)
#define MFMA_YF() do { \
    _Pragma("unroll") \
    for (int ks = 0; ks < 2; ++ks) { \
      const int xoo = ks * 32 + h * 8; \
      bf16x8 a0 = *(const bf16x8*)(sX + (wr * 32 + 0  + r) * SXW + xoo); \
      bf16x8 a1 = *(const bf16x8*)(sX + (wr * 32 + 16 + r) * SXW + xoo); \
      _Pragma("unroll") \
      for (int bg = 0; bg < 4; ++bg) { \
        bf16x8 bb = *(const bf16x8*)(sW + (wc * 64 + bg * 16 + r) * SXW + xoo); \
        yacc[0][bg] = __builtin_amdgcn_mfma_f32_16x16x32_bf16(a0, bb, yacc[0][bg], 0, 0, 0); \
        yacc[1][bg] = __builtin_amdgcn_mfma_f32_16x16x32_bf16(a1, bb, yacc[1][bg], 0, 0, 0); \
      } } } while (0)

  f32x4 zacc[2][4];
#pragma unroll
  for (int a = 0; a < 2; ++a)
#pragma unroll
    for (int b = 0; b < 4; ++b) zacc[a][b] = f32x4{0.f, 0.f, 0.f, 0.f};

  LOAD_X(0); LOAD_W(0, 0);

  for (int gc = 0; gc < 4; ++gc) {
    f32x4 yacc[2][4];
#pragma unroll
    for (int a = 0; a < 2; ++a)
#pragma unroll
      for (int b = 0; b < 4; ++b) yacc[a][b] = f32x4{0.f, 0.f, 0.f, 0.f};

    for (int xc = 0; xc < 7; ++xc) {
      __syncthreads();
      STORE_XW();
      __syncthreads();
      LOAD_X(xc + 1); LOAD_W(gc, xc + 1);
      MFMA_YF();
    }
    __syncthreads();
    STORE_XW();
    __syncthreads();
    {
      const float4* p0 = (const float4*)(cs + 0 * cstep + gc * 128);
      const float4* p1 = (const float4*)(cs + 1 * cstep + gc * 128);
      const float4* p2 = (const float4*)(cs + 2 * cstep + gc * 128);
      const float4* p3 = (const float4*)(cs + 3 * cstep + gc * 128);
      pc0 = p0[0]; pc1 = p0[1];
      pc2 = p1[0]; pc3 = p1[1];
      pc4 = p2[0]; pc5 = p2[1];
      pc6 = p3[0]; pc7 = p3[1];
    }
    MFMA_YF();

#pragma unroll
    for (int aj = 0; aj < 2; ++aj)
#pragma unroll
      for (int bg = 0; bg < 4; ++bg)
#pragma unroll
        for (int reg = 0; reg < 4; ++reg)
          sY[(wr * 32 + aj * 16 + h * 4 + reg) * SYC + (wc * 64 + bg * 16 + r)] =
              (unsigned short)(__float_as_uint(yacc[aj][bg][reg]) >> 16);
    __syncthreads();
    *(uint4*)(cd + 0 * 32 * SYC) = pack8(pc0, pc1);
    *(uint4*)(cd + 1 * 32 * SYC) = pack8(pc2, pc3);
    *(uint4*)(cd + 2 * 32 * SYC) = pack8(pc4, pc5);
    *(uint4*)(cd + 3 * 32 * SYC) = pack8(pc6, pc7);
    __syncthreads();
    if (gc < 3) { LOAD_X(0); LOAD_W(gc + 1, 0); }
#pragma unroll
    for (int ks = 0; ks < 4; ++ks) {
      const int go = ks * 32 + h * 8;
      bf16x8 a0 = *(const bf16x8*)(sC + (wr * 32 + 0  + r) * SYC + go);
      bf16x8 a1 = *(const bf16x8*)(sC + (wr * 32 + 16 + r) * SYC + go);
#pragma unroll
      for (int bj = 0; bj < 4; ++bj) {
        bf16x8 bb = *(const bf16x8*)(sY + (wc * 64 + bj * 16 + r) * SYC + go);
        zacc[0][bj] = __builtin_amdgcn_mfma_f32_16x16x32_bf16(a0, bb, zacc[0][bj], 0, 0, 0);
        zacc[1][bj] = __builtin_amdgcn_mfma_f32_16x16x32_bf16(a1, bb, zacc[1][bj], 0, 0, 0);
      }
    }
  }
  __syncthreads();
#pragma unroll
  for (int ai = 0; ai < 2; ++ai)
#pragma unroll
    for (int bj = 0; bj < 4; ++bj)
#pragma unroll
      for (int reg = 0; reg < 4; ++reg)
        sZ[(wr * 32 + ai * 16 + h * 4 + reg) * SZS + (wc * 64 + bj * 16 + r)] =
            zacc[ai][bj][reg];
  __syncthreads();

  const int row = wave * 16 + (lane >> 2);
  const int c0l = lane & 3;
  float mx = -3.4e38f;
#pragma unroll
  for (int m = 0; m < 32; ++m) mx = fmaxf(mx, sZ[row * SZS + c0l + m * 4]);
  mx = fmaxf(mx, __shfl_xor(mx, 1));
  mx = fmaxf(mx, __shfl_xor(mx, 2));
  float sum = 0.f;
#pragma unroll
  for (int m = 0; m < 32; ++m) sum += __expf(sZ[row * SZS + c0l + m * 4] - mx);
  sum += __shfl_xor(sum, 1);
  sum += __shfl_xor(sum, 2);
  float val = (c0l == 0) ? (sZ[row * SZS + row] - (__logf(sum) + mx)) : 0.f;
#pragma unroll
  for (int off = 1; off < 64; off <<= 1) val += __shfl_xor(val, off);
  if (lane == 0) sRed[wave] = val;
  __syncthreads();
  if (tid == 0) {
    float bs = 0.f;
#pragma unroll
    for (int w2 = 0; w2 < 8; ++w2) bs += sRed[w2];
    atomicAdd(out + k, bs);
  }
#undef LOAD_X
#undef LOAD_W
#undef STORE_XW
#undef MFMA_YF
}

extern "C" void kernel_launch(void* const* d_in, const int* in_sizes, int n_in,
                              void* d_out, int out_size, void* d_ws, size_t ws_size,
                              hipStream_t stream) {
  const float* C = (const float*)d_in[0];
  const float* X = (const float*)d_in[1];
  const float* W = (const float*)d_in[2];
  // d_in[3] (bias) intentionally unused: j-independent bias cancels in Zdiag - lse
  float* out = (float*)d_out;

  const size_t NX = (size_t)128 * Tn * FXn;        // 134,217,728 elems (X)
  const size_t NW = (size_t)4 * FCn * FXn;         // 1,048,576 elems
  const size_t WS_W   = NW * 2;                    // 2 MB
  const size_t WS_MID = WS_W + NX * 2;             // + Xbf = 270,532,608

  hipLaunchKernelGGL(zero4, dim3(1), dim3(64), 0, stream, out);

  if (ws_size >= WS_MID) {
    unsigned short* Wbf = (unsigned short*)d_ws;
    unsigned short* Xbf = (unsigned short*)((char*)d_ws + WS_W);
    hipLaunchKernelGGL(tobf16, dim3((unsigned)(NW / 1024)), dim3(256), 0, stream, W, Wbf);
    hipLaunchKernelGGL(tobf16, dim3((unsigned)(NX / 1024)), dim3(256), 0, stream, X, Xbf);
    hipLaunchKernelGGL(infonce_v9, dim3(2047 * 4), dim3(256), 0, stream,
                       C, Xbf, Wbf, out);
  } else if (ws_size >= WS_W) {
    hipLaunchKernelGGL(tobf16, dim3((unsigned)(NW / 1024)), dim3(256), 0, stream,
                       W, (unsigned short*)d_ws);
    hipLaunchKernelGGL(infonce_main<true>, dim3(2047 * 4), dim3(512), 0, stream,
                       C, X, (const void*)d_ws, out);
  } else {
    hipLaunchKernelGGL(infonce_main<false>, dim3(2047 * 4), dim3(512), 0, stream,
                       C, X, (const void*)W, out);
  }
  hipLaunchKernelGGL(finalize4, dim3(1), dim3(64), 0, stream, out);
}